// Round 2
// baseline (506.793 us; speedup 1.0000x reference)
//
#include <hip/hip_runtime.h>

#define MDIM 4096
#define KDIM 4096
#define NDIM 11008
#define NGROUPS 32

#define BM 256
#define BN 256
#define BK 64
#define NT (KDIM / BK)   // 64 K-tiles
#define KB (KDIM * 2)    // row stride in bytes (8192)

typedef _Float16 f16x8 __attribute__((ext_vector_type(8)));
typedef float f32x4 __attribute__((ext_vector_type(4)));

typedef const unsigned int __attribute__((address_space(1))) *gas_t;
typedef unsigned int __attribute__((address_space(3))) *las_t;

__device__ __forceinline__ void gld_lds16(const void *g, void *l) {
  __builtin_amdgcn_global_load_lds((gas_t)g, (las_t)l, 16, 0, 0);
}

// Raw barrier with memory clobber (no implicit vm/lgkm drain).
#define BAR() asm volatile("s_barrier" ::: "memory")
#define VMW8() asm volatile("s_waitcnt vmcnt(8)" ::: "memory")
#define VMW0() asm volatile("s_waitcnt vmcnt(0)" ::: "memory")
// Pin {reads, stages} before the MFMA cluster of each phase.
#define FENCE() __builtin_amdgcn_sched_barrier(0)

// ---------------- prepass: A fp32 -> f16 ----------------
__global__ __launch_bounds__(256) void cvt_a_kernel(const float *__restrict__ a,
                                                    _Float16 *__restrict__ o) {
  const int n8 = (MDIM * KDIM) / 8;
  for (int i = blockIdx.x * blockDim.x + threadIdx.x; i < n8;
       i += gridDim.x * blockDim.x) {
    const float4 v0 = *(const float4 *)(a + (size_t)i * 8);
    const float4 v1 = *(const float4 *)(a + (size_t)i * 8 + 4);
    f16x8 h;
    h[0] = (_Float16)v0.x; h[1] = (_Float16)v0.y;
    h[2] = (_Float16)v0.z; h[3] = (_Float16)v0.w;
    h[4] = (_Float16)v1.x; h[5] = (_Float16)v1.y;
    h[6] = (_Float16)v1.z; h[7] = (_Float16)v1.w;
    *(f16x8 *)(o + (size_t)i * 8) = h;
  }
}

// ---------------- prepass: W int32 -> f16 * scale ----------------
__global__ __launch_bounds__(256) void cvt_w_kernel(const int *__restrict__ w,
                                                    const float *__restrict__ s,
                                                    _Float16 *__restrict__ o) {
  const int n8 = (NDIM * KDIM) / 8;
  for (int i = blockIdx.x * blockDim.x + threadIdx.x; i < n8;
       i += gridDim.x * blockDim.x) {
    const size_t base = (size_t)i * 8;
    const int row = (int)(base >> 12);             // /KDIM
    const int g = ((int)(base & (KDIM - 1))) >> 7; // /GROUPSIZE
    const float sc = s[row * NGROUPS + g];
    const int4 w0 = *(const int4 *)(w + base);
    const int4 w1 = *(const int4 *)(w + base + 4);
    f16x8 h;
    h[0] = (_Float16)((float)w0.x * sc); h[1] = (_Float16)((float)w0.y * sc);
    h[2] = (_Float16)((float)w0.z * sc); h[3] = (_Float16)((float)w0.w * sc);
    h[4] = (_Float16)((float)w1.x * sc); h[5] = (_Float16)((float)w1.y * sc);
    h[6] = (_Float16)((float)w1.z * sc); h[7] = (_Float16)((float)w1.w * sc);
    *(f16x8 *)(o + base) = h;
  }
}

// ---------------- main GEMM: 256x256 tile, BK=64, 8 waves ------------------
// Round-0 overlapped skeleton (counted-lgkm prefetch under MFMA) with:
//  * BOTH A and B staged 2 tiles ahead into buf[b] (A restage after BAR2,
//    B restage after BAR1), so the publish-point wait is vmcnt(8) retiring
//    loads issued a full tile earlier -> never blocks.
//  * Quadrant order Q00,Q01,Q11,Q10 with period-2 B-register role swap so
//    the regs-only Q10 runs AFTER the publish barrier and shadows the
//    12-read next-tile fragment prefetch burst.
//  * 3 barriers/tile: BAR1 (Bs[b] reads retired), BAR2 (As[b] reads
//    retired), BAR3 (publish buf[b^1]).
// LDS XOR-swizzle (16B involution): phys_koff = koff ^ ((row&7)*16), applied
// to the pre-swizzled staging source AND the ds_read address.
__global__ __launch_bounds__(512, 2) void gemm_8phase(
    const _Float16 *__restrict__ Ah, const _Float16 *__restrict__ Wh,
    float *__restrict__ C) {
  __shared__ __align__(16) _Float16 As[2][BM * BK];
  __shared__ __align__(16) _Float16 Bs[2][BN * BK];

  const int tid = threadIdx.x;
  const int l = tid & 63;
  const int w = tid >> 6;   // wave 0..7
  const int wm = w >> 2;    // 0..1 (M half)
  const int wn = w & 3;     // 0..3 (N quarter)

  // XCD-aware bijective swizzle: 688 blocks, 86 per XCD.
  const int wg = blockIdx.x;
  const int swz = (wg & 7) * 86 + (wg >> 3);
  const int bx = swz / 16;   // N tile 0..42
  const int by = swz % 16;   // M tile 0..15

  // staging source (pre-swizzled per lane)
  const int srow = l >> 3;
  const int gk = ((l & 7) ^ srow) * 16;
  const char *Ag =
      (const char *)Ah + (size_t)(by * BM + w * 8 + srow) * KB + gk;
  const char *Bg =
      (const char *)Wh + (size_t)(bx * BN + w * 8 + srow) * KB + gk;

  // fragment-read offsets (bytes)
  const int laneRow = (l & 15) * (BK * 2);
  const int kx0 = ((l >> 4) * 16) ^ ((l & 7) * 16);
  const int kx1 = kx0 ^ 64;

  f32x4 acc[8][4] = {};
  f16x8 af0[4][2], af1[4][2], bf0[2][2], bf1[2][2];

#define STAGE2_A(KT, B, S0)                                                   \
  {                                                                           \
    const char *ap_ = Ag + (size_t)(KT) * (BK * 2);                           \
    gld_lds16(ap_ + (size_t)(S0) * (64 * KB),                                 \
              (void *)&As[B][(S0) * 4096 + w * 512]);                         \
    gld_lds16(ap_ + (size_t)((S0) + 1) * (64 * KB),                           \
              (void *)&As[B][((S0) + 1) * 4096 + w * 512]);                   \
  }

#define STAGE2_B(KT, B, S0)                                                   \
  {                                                                           \
    const char *bp_ = Bg + (size_t)(KT) * (BK * 2);                           \
    gld_lds16(bp_ + (size_t)(S0) * (64 * KB),                                 \
              (void *)&Bs[B][(S0) * 4096 + w * 512]);                         \
    gld_lds16(bp_ + (size_t)((S0) + 1) * (64 * KB),                           \
              (void *)&Bs[B][((S0) + 1) * 4096 + w * 512]);                   \
  }

#define LDA_Q(DST, QM, BASE)                                                  \
  {                                                                           \
    const char *ba_ = (BASE) + (wm * 128 + (QM) * 64) * (BK * 2) + laneRow;   \
    _Pragma("unroll") for (int mi = 0; mi < 4; ++mi) {                        \
      DST[mi][0] = *(const f16x8 *)(ba_ + mi * 2048 + kx0);                   \
      DST[mi][1] = *(const f16x8 *)(ba_ + mi * 2048 + kx1);                   \
    }                                                                         \
  }

#define LDB_Q(DST, QN, BASE)                                                  \
  {                                                                           \
    const char *bb_ = (BASE) + (wn * 64 + (QN) * 32) * (BK * 2) + laneRow;    \
    _Pragma("unroll") for (int nj = 0; nj < 2; ++nj) {                        \
      DST[nj][0] = *(const f16x8 *)(bb_ + nj * 2048 + kx0);                   \
      DST[nj][1] = *(const f16x8 *)(bb_ + nj * 2048 + kx1);                   \
    }                                                                         \
  }

#define MMA_Q(AF, BF, QM, QN)                                                 \
  __builtin_amdgcn_s_setprio(1);                                              \
  _Pragma("unroll") for (int ks = 0; ks < 2; ++ks)                            \
      _Pragma("unroll") for (int mi = 0; mi < 4; ++mi)                        \
          _Pragma("unroll") for (int nj = 0; nj < 2; ++nj)                    \
              acc[(QM) * 4 + mi][(QN) * 2 + nj] =                             \
                  __builtin_amdgcn_mfma_f32_16x16x32_f16(                     \
                      AF[mi][ks], BF[nj][ks],                                 \
                      acc[(QM) * 4 + mi][(QN) * 2 + nj], 0, 0, 0);            \
  __builtin_amdgcn_s_setprio(0);

  // TILE_BODY(t, b, B0r, B1r): B0r holds this tile's QN=0 fragments
  // (prefetched at previous tile's tail), B1r is loaded with QN=1 here and
  // its registers are reused at the tail for the NEXT tile's QN=0 prefetch.
#define TILE_BODY(TT, BIDX, B0r, B1r)                                         \
  {                                                                           \
    const char *Ab = (const char *)&As[BIDX][0];                              \
    const char *Bb = (const char *)&Bs[BIDX][0];                              \
    const char *An = (const char *)&As[(BIDX) ^ 1][0];                        \
    const char *Bn = (const char *)&Bs[(BIDX) ^ 1][0];                        \
    const bool s1 = ((TT) + 1 < NT);                                          \
    const bool s2 = ((TT) + 2 < NT);                                          \
    /* P1: load B QN=1; Q00 runs on prefetched af0/B0r (counted lgkm) */      \
    LDB_Q(B1r, 1, Bb);                                                        \
    FENCE();                                                                  \
    MMA_Q(af0, B0r, 0, 0);                                                    \
    /* P2: load A QM=1; Q01 needs B1r (loaded one phase ago) */               \
    LDA_Q(af1, 1, Ab);                                                        \
    FENCE();                                                                  \
    MMA_Q(af0, B1r, 0, 1);                                                    \
    BAR(); /* BAR1: all waves past Q01 lgkm -> Bs[b] reads retired */         \
    /* P3: restage B(t+2) into Bs[b]; Q11 needs af1 */                        \
    if (s2) { STAGE2_B((TT) + 2, BIDX, 0); STAGE2_B((TT) + 2, BIDX, 2); }     \
    FENCE();                                                                  \
    MMA_Q(af1, B1r, 1, 1);                                                    \
    BAR(); /* BAR2: all waves past Q11 lgkm -> As[b] reads retired */         \
    /* P4: restage A(t+2); vmcnt(8) retires X(t+1) (issued last tile); */     \
    /* publish; prefetch next tile's frags SHADOWED by regs-only Q10. */      \
    if (s2) { STAGE2_A((TT) + 2, BIDX, 0); STAGE2_A((TT) + 2, BIDX, 2);       \
              VMW8(); }                                                       \
    else { VMW0(); }                                                          \
    BAR(); /* BAR3: publish As/Bs[b^1] = X(t+1) */                            \
    if (s1) { LDA_Q(af0, 0, An); LDB_Q(B1r, 0, Bn); }                         \
    FENCE();                                                                  \
    MMA_Q(af1, B0r, 1, 0);                                                    \
  }

  // prologue: stage X(0) (oldest 8) then X(1); retire X(0); prefetch frags.
  STAGE2_A(0, 0, 0); STAGE2_A(0, 0, 2);
  STAGE2_B(0, 0, 0); STAGE2_B(0, 0, 2);
  STAGE2_A(1, 1, 0); STAGE2_A(1, 1, 2);
  STAGE2_B(1, 1, 0); STAGE2_B(1, 1, 2);
  VMW8();
  BAR();
  LDA_Q(af0, 0, (const char *)&As[0][0]);
  LDB_Q(bf0, 0, (const char *)&Bs[0][0]);

  for (int t = 0; t < NT; t += 2) {
    TILE_BODY(t, 0, bf0, bf1);
    TILE_BODY(t + 1, 1, bf1, bf0);
  }

#undef TILE_BODY
#undef STAGE2_A
#undef STAGE2_B
#undef LDA_Q
#undef LDB_Q
#undef MMA_Q

  // C/D layout: col = lane&15, row = (lane>>4)*4 + reg
  const int fr = l & 15, fq = l >> 4;
  float *Cb = C + (size_t)(by * BM + wm * 128) * NDIM + bx * BN + wn * 64;
#pragma unroll
  for (int i = 0; i < 8; ++i)
#pragma unroll
    for (int j = 0; j < 4; ++j)
#pragma unroll
      for (int r = 0; r < 4; ++r)
        Cb[(size_t)(i * 16 + fq * 4 + r) * NDIM + j * 16 + fr] = acc[i][j][r];
}

// ---------------- fallback: fused dequant GEMM (no workspace needed) -------
__global__ __launch_bounds__(256) void gemm_fused(const float *__restrict__ A,
                                                  const int *__restrict__ W,
                                                  const float *__restrict__ S,
                                                  float *__restrict__ C) {
  __shared__ _Float16 Asf[128 * 64];
  __shared__ _Float16 Bsf[128 * 64];
  const int tid = threadIdx.x;
  const int lane = tid & 63;
  const int wv = tid >> 6;
  const int wm = wv >> 1, wn = wv & 1;
  const int bx = blockIdx.x, by = blockIdx.y;
  const int srow = tid >> 1;
  const int skof = (tid & 1) * 32;

  const float *Ab = A + (size_t)(by * 128 + srow) * KDIM + skof;
  const int *Wb = W + (size_t)(bx * 128 + srow) * KDIM + skof;
  const float *Sb = S + (size_t)(bx * 128 + srow) * NGROUPS;

  f32x4 acc[4][4] = {};
  float4 ar[8];
  int4 wr[8];
  float sc;

#pragma unroll
  for (int u = 0; u < 8; ++u) {
    ar[u] = *(const float4 *)(Ab + u * 4);
    wr[u] = *(const int4 *)(Wb + u * 4);
  }
  sc = Sb[0];

  const int fr = lane & 15;
  const int fq = lane >> 4;
  const int kbase = fq * 8;

  for (int kt = 0; kt < KDIM / 64; ++kt) {
    __syncthreads();
    _Float16 *Ad = &Asf[srow * 64 + skof];
    _Float16 *Bd = &Bsf[srow * 64 + skof];
#pragma unroll
    for (int u = 0; u < 4; ++u) {
      const float4 a0 = ar[2 * u], a1 = ar[2 * u + 1];
      const int4 b0 = wr[2 * u], b1 = wr[2 * u + 1];
      f16x8 ha, hb;
      ha[0] = (_Float16)a0.x; ha[1] = (_Float16)a0.y;
      ha[2] = (_Float16)a0.z; ha[3] = (_Float16)a0.w;
      ha[4] = (_Float16)a1.x; ha[5] = (_Float16)a1.y;
      ha[6] = (_Float16)a1.z; ha[7] = (_Float16)a1.w;
      hb[0] = (_Float16)((float)b0.x * sc); hb[1] = (_Float16)((float)b0.y * sc);
      hb[2] = (_Float16)((float)b0.z * sc); hb[3] = (_Float16)((float)b0.w * sc);
      hb[4] = (_Float16)((float)b1.x * sc); hb[5] = (_Float16)((float)b1.y * sc);
      hb[6] = (_Float16)((float)b1.z * sc); hb[7] = (_Float16)((float)b1.w * sc);
      *(f16x8 *)(Ad + u * 8) = ha;
      *(f16x8 *)(Bd + u * 8) = hb;
    }
    if (kt + 1 < KDIM / 64) {
      const float *An = Ab + (kt + 1) * 64;
      const int *Wn = Wb + (kt + 1) * 64;
#pragma unroll
      for (int u = 0; u < 8; ++u) {
        ar[u] = *(const float4 *)(An + u * 4);
        wr[u] = *(const int4 *)(Wn + u * 4);
      }
      sc = Sb[(kt + 1) >> 1];
    }
    __syncthreads();
#pragma unroll
    for (int ks = 0; ks < 2; ++ks) {
      f16x8 afv[4], bfv[4];
      const int kof = ks * 32 + kbase;
#pragma unroll
      for (int i = 0; i < 4; ++i) {
        afv[i] = *(const f16x8 *)&Asf[(wm * 64 + i * 16 + fr) * 64 + kof];
        bfv[i] = *(const f16x8 *)&Bsf[(wn * 64 + i * 16 + fr) * 64 + kof];
      }
#pragma unroll
      for (int i = 0; i < 4; ++i)
#pragma unroll
        for (int j = 0; j < 4; ++j)
          acc[i][j] = __builtin_amdgcn_mfma_f32_16x16x32_f16(afv[i], bfv[j],
                                                             acc[i][j], 0, 0, 0);
    }
  }

  float *Cb = C + (size_t)(by * 128 + wm * 64) * NDIM + bx * 128 + wn * 64;
#pragma unroll
  for (int i = 0; i < 4; ++i)
#pragma unroll
    for (int j = 0; j < 4; ++j)
#pragma unroll
      for (int r = 0; r < 4; ++r)
        Cb[(size_t)(i * 16 + fq * 4 + r) * NDIM + j * 16 + fr] = acc[i][j][r];
}

extern "C" void kernel_launch(void *const *d_in, const int *in_sizes, int n_in,
                              void *d_out, int out_size, void *d_ws,
                              size_t ws_size, hipStream_t stream) {
  (void)in_sizes; (void)n_in; (void)out_size;
  const float *A = (const float *)d_in[0];
  const int *W = (const int *)d_in[1];
  const float *S = (const float *)d_in[2];
  float *C = (float *)d_out;

  const size_t needA = (size_t)MDIM * KDIM * sizeof(_Float16);
  const size_t needW = (size_t)NDIM * KDIM * sizeof(_Float16);

  if (ws_size >= needA + needW) {
    _Float16 *Ahp = (_Float16 *)d_ws;
    _Float16 *Whp = (_Float16 *)((char *)d_ws + needA);
    cvt_a_kernel<<<2048, 256, 0, stream>>>(A, Ahp);
    cvt_w_kernel<<<2048, 256, 0, stream>>>(W, S, Whp);
    gemm_8phase<<<(MDIM / BM) * (NDIM / BN), 512, 0, stream>>>(Ahp, Whp, C);
  } else {
    dim3 grid(NDIM / 128, MDIM / 128);
    gemm_fused<<<grid, 256, 0, stream>>>(A, W, S, C);
  }
}

// Round 3
// 481.311 us; speedup vs baseline: 1.0529x; 1.0529x over previous
//
#include <hip/hip_runtime.h>

#define MDIM 4096
#define KDIM 4096
#define NDIM 11008
#define NGROUPS 32

#define BM 256
#define BN 256
#define BK 64
#define NT (KDIM / BK)   // 64 K-tiles
#define KB (KDIM * 2)    // row stride in bytes (8192)

typedef _Float16 f16x8 __attribute__((ext_vector_type(8)));
typedef float f32x4 __attribute__((ext_vector_type(4)));
typedef float f32x16 __attribute__((ext_vector_type(16)));

typedef const unsigned int __attribute__((address_space(1))) *gas_t;
typedef unsigned int __attribute__((address_space(3))) *las_t;

__device__ __forceinline__ void gld_lds16(const void *g, void *l) {
  __builtin_amdgcn_global_load_lds((gas_t)g, (las_t)l, 16, 0, 0);
}

// Raw barrier with memory clobber (no implicit vm/lgkm drain).
#define BAR() asm volatile("s_barrier" ::: "memory")
#define VMW4() asm volatile("s_waitcnt vmcnt(4)" ::: "memory")
#define VMW0() asm volatile("s_waitcnt vmcnt(0)" ::: "memory")
// Pin {reads, glds} before the MFMA cluster of each phase.
#define FENCE() __builtin_amdgcn_sched_barrier(0)

// ---------------- prepass: A fp32 -> f16 ----------------
__global__ __launch_bounds__(256) void cvt_a_kernel(const float *__restrict__ a,
                                                    _Float16 *__restrict__ o) {
  const int n8 = (MDIM * KDIM) / 8;
  for (int i = blockIdx.x * blockDim.x + threadIdx.x; i < n8;
       i += gridDim.x * blockDim.x) {
    const float4 v0 = *(const float4 *)(a + (size_t)i * 8);
    const float4 v1 = *(const float4 *)(a + (size_t)i * 8 + 4);
    f16x8 h;
    h[0] = (_Float16)v0.x; h[1] = (_Float16)v0.y;
    h[2] = (_Float16)v0.z; h[3] = (_Float16)v0.w;
    h[4] = (_Float16)v1.x; h[5] = (_Float16)v1.y;
    h[6] = (_Float16)v1.z; h[7] = (_Float16)v1.w;
    *(f16x8 *)(o + (size_t)i * 8) = h;
  }
}

// ---------------- prepass: W int32 -> f16 * scale ----------------
__global__ __launch_bounds__(256) void cvt_w_kernel(const int *__restrict__ w,
                                                    const float *__restrict__ s,
                                                    _Float16 *__restrict__ o) {
  const int n8 = (NDIM * KDIM) / 8;
  for (int i = blockIdx.x * blockDim.x + threadIdx.x; i < n8;
       i += gridDim.x * blockDim.x) {
    const size_t base = (size_t)i * 8;
    const int row = (int)(base >> 12);             // /KDIM
    const int g = ((int)(base & (KDIM - 1))) >> 7; // /GROUPSIZE
    const float sc = s[row * NGROUPS + g];
    const int4 w0 = *(const int4 *)(w + base);
    const int4 w1 = *(const int4 *)(w + base + 4);
    f16x8 h;
    h[0] = (_Float16)((float)w0.x * sc); h[1] = (_Float16)((float)w0.y * sc);
    h[2] = (_Float16)((float)w0.z * sc); h[3] = (_Float16)((float)w0.w * sc);
    h[4] = (_Float16)((float)w1.x * sc); h[5] = (_Float16)((float)w1.y * sc);
    h[6] = (_Float16)((float)w1.z * sc); h[7] = (_Float16)((float)w1.w * sc);
    *(f16x8 *)(o + base) = h;
  }
}

// ---------------- main GEMM: 256x256 tile, BK=64, 8 waves ------------------
// R0 schedule (best measured: 413 us), MFMA shape switched to 32x32x16_f16:
// half the MFMA instructions for the same work at a higher measured rate
// (2382 vs 2075 TF ubench), identical ds_read counts and register footprint.
// Pipelined phases: ds_reads for phase p+1 issued before phase p's MFMAs,
// retired by compiler-counted lgkmcnt (never drained). 2 barriers/tile.
// LDS XOR-swizzle (16B involution): phys_slot = slot ^ (row&7), applied to
// the pre-swizzled staging source AND the ds_read address.
// Fragment layouts (32x32x16_f16):
//   A: lane holds A[row=l&31][k=(l>>5)*8 .. +7]  (one ds_read_b128)
//   B: lane holds W[col=l&31][k=(l>>5)*8 .. +7]
//   C/D: col = l&31, row = (reg&3) + 8*(reg>>2) + 4*(l>>5)   [m74/m101]
__global__ __launch_bounds__(512, 2) void gemm_8phase(
    const _Float16 *__restrict__ Ah, const _Float16 *__restrict__ Wh,
    float *__restrict__ C) {
  __shared__ __align__(16) _Float16 As[2][BM * BK];
  __shared__ __align__(16) _Float16 Bs[2][BN * BK];

  const int tid = threadIdx.x;
  const int l = tid & 63;
  const int w = tid >> 6;   // wave 0..7
  const int wm = w >> 2;    // 0..1 (M half)
  const int wn = w & 3;     // 0..3 (N quarter)

  // XCD-aware bijective swizzle: 688 blocks, 86 per XCD.
  const int wg = blockIdx.x;
  const int swz = (wg & 7) * 86 + (wg >> 3);
  const int bx = swz / 16;   // N tile 0..42
  const int by = swz % 16;   // M tile 0..15

  // staging source (pre-swizzled per lane)
  const int srow = l >> 3;
  const int gk = ((l & 7) ^ srow) * 16;
  const char *Ag =
      (const char *)Ah + (size_t)(by * BM + w * 8 + srow) * KB + gk;
  const char *Bg =
      (const char *)Wh + (size_t)(bx * BN + w * 8 + srow) * KB + gk;

  // fragment-read offsets (bytes): row = l&31 (128 B rows), k-slot for
  // k-step kk is ((kk*2 + (l>>5)) ^ (l&7)) * 16  (XOR involution).
  const int laneRow32 = (l & 31) * 128;
  int kxs[4];
#pragma unroll
  for (int kk = 0; kk < 4; ++kk)
    kxs[kk] = ((((kk << 1) | (l >> 5)) ^ (l & 7)) << 4);

  f32x16 acc[4][2] = {};            // [M-frag 0..3][N-frag 0..1], 16 f32 each
  f16x8 af0[2][4], af1[2][4];       // [mi][kk] quadrant A fragments
  f16x8 bf0[4], bf1[4];             // [kk] quadrant B fragments

#define STAGE2_A(KT, B, S0)                                                   \
  {                                                                           \
    const char *ap_ = Ag + (size_t)(KT) * (BK * 2);                           \
    gld_lds16(ap_ + (size_t)(S0) * (64 * KB),                                 \
              (void *)&As[B][(S0) * 4096 + w * 512]);                         \
    gld_lds16(ap_ + (size_t)((S0) + 1) * (64 * KB),                           \
              (void *)&As[B][((S0) + 1) * 4096 + w * 512]);                   \
  }

#define STAGE2_B(KT, B, S0)                                                   \
  {                                                                           \
    const char *bp_ = Bg + (size_t)(KT) * (BK * 2);                           \
    gld_lds16(bp_ + (size_t)(S0) * (64 * KB),                                 \
              (void *)&Bs[B][(S0) * 4096 + w * 512]);                         \
    gld_lds16(bp_ + (size_t)((S0) + 1) * (64 * KB),                           \
              (void *)&Bs[B][((S0) + 1) * 4096 + w * 512]);                   \
  }

  // Quadrant = 64 M-rows (2x 32-row frags) x 32 N-cols (1 frag) x BK.
#define LDA_Q(DST, QM, BASE)                                                  \
  {                                                                           \
    const char *ba_ = (BASE) + (wm * 128 + (QM) * 64) * (BK * 2) + laneRow32; \
    _Pragma("unroll") for (int mi = 0; mi < 2; ++mi)                          \
        _Pragma("unroll") for (int kk = 0; kk < 4; ++kk)                      \
            DST[mi][kk] = *(const f16x8 *)(ba_ + mi * 4096 + kxs[kk]);        \
  }

#define LDB_Q(DST, QN, BASE)                                                  \
  {                                                                           \
    const char *bb_ = (BASE) + (wn * 64 + (QN) * 32) * (BK * 2) + laneRow32;  \
    _Pragma("unroll") for (int kk = 0; kk < 4; ++kk)                          \
        DST[kk] = *(const f16x8 *)(bb_ + kxs[kk]);                            \
  }

#define MMA_Q(AF, BF, QM, QN)                                                 \
  __builtin_amdgcn_s_setprio(1);                                              \
  _Pragma("unroll") for (int kk = 0; kk < 4; ++kk)                            \
      _Pragma("unroll") for (int mi = 0; mi < 2; ++mi)                        \
          acc[(QM) * 2 + mi][QN] = __builtin_amdgcn_mfma_f32_32x32x16_f16(    \
              AF[mi][kk], BF[kk], acc[(QM) * 2 + mi][QN], 0, 0, 0);           \
  __builtin_amdgcn_s_setprio(0);

  // prologue: A(0),B(0),B(1); retire A0/B0, keep B1 in flight; prefetch P1.
  STAGE2_A(0, 0, 0); STAGE2_A(0, 0, 2);
  STAGE2_B(0, 0, 0); STAGE2_B(0, 0, 2);
  STAGE2_B(1, 1, 0); STAGE2_B(1, 1, 2);
  VMW4();
  BAR();
  LDA_Q(af0, 0, (const char *)&As[0][0]);
  LDB_Q(bf0, 0, (const char *)&Bs[0][0]);

#pragma unroll 2
  for (int t = 0; t < NT; ++t) {
    const int b = t & 1;
    const char *Ab = (const char *)&As[b][0];
    const char *Bb = (const char *)&Bs[b][0];
    const char *An = (const char *)&As[b ^ 1][0];
    const char *Bn = (const char *)&Bs[b ^ 1][0];
    const bool s1 = (t + 1 < NT);
    const bool s2 = (t + 2 < NT);

    // P1: prefetch bf1; stage A(t+1) h1; MFMA Q00 (counted lgkm)
    LDB_Q(bf1, 1, Bb);
    if (s1) STAGE2_A(t + 1, b ^ 1, 0);
    FENCE();
    MMA_Q(af0, bf0, 0, 0);

    // P2: prefetch af1; stage A(t+1) h2; MFMA Q01 (counted lgkm)
    LDA_Q(af1, 1, Ab);
    if (s1) STAGE2_A(t + 1, b ^ 1, 2);
    FENCE();
    MMA_Q(af0, bf1, 0, 1);
    BAR();  // all waves' reads of Bs[b] retired -> B-buf b reusable

    // P3: stage B(t+2) h1 -> Bs[b]; MFMA Q11
    if (s2) STAGE2_B(t + 2, b, 0);
    FENCE();
    MMA_Q(af1, bf1, 1, 1);

    // P4: stage B(t+2) h2; MFMA Q10 (regs only); counted vm retire; publish
    if (s2) STAGE2_B(t + 2, b, 2);
    FENCE();
    MMA_Q(af1, bf0, 1, 0);
    if (s2) { VMW4(); } else { VMW0(); }
    BAR();  // publish As[b^1]=A(t+1), Bs[b^1]=B(t+1)
    if (s1) {  // prefetch next tile's P1 fragments
      LDA_Q(af0, 0, An);
      LDB_Q(bf0, 0, Bn);
    }
  }

#undef STAGE2_A
#undef STAGE2_B
#undef LDA_Q
#undef LDB_Q
#undef MMA_Q

  // C/D layout (32x32): col = l&31, row = (reg&3) + 8*(reg>>2) + 4*(l>>5)
  const int col = l & 31;
  const int hh = l >> 5;
  float *Cb = C + (size_t)(by * BM + wm * 128) * NDIM + bx * BN + wn * 64 + col;
#pragma unroll
  for (int ai = 0; ai < 4; ++ai)
#pragma unroll
    for (int nj = 0; nj < 2; ++nj)
#pragma unroll
      for (int r = 0; r < 16; ++r) {
        const int row = ai * 32 + (r & 3) + 8 * (r >> 2) + 4 * hh;
        Cb[(size_t)row * NDIM + nj * 32] = acc[ai][nj][r];
      }
}

// ---------------- fallback: fused dequant GEMM (no workspace needed) -------
__global__ __launch_bounds__(256) void gemm_fused(const float *__restrict__ A,
                                                  const int *__restrict__ W,
                                                  const float *__restrict__ S,
                                                  float *__restrict__ C) {
  __shared__ _Float16 Asf[128 * 64];
  __shared__ _Float16 Bsf[128 * 64];
  const int tid = threadIdx.x;
  const int lane = tid & 63;
  const int wv = tid >> 6;
  const int wm = wv >> 1, wn = wv & 1;
  const int bx = blockIdx.x, by = blockIdx.y;
  const int srow = tid >> 1;
  const int skof = (tid & 1) * 32;

  const float *Ab = A + (size_t)(by * 128 + srow) * KDIM + skof;
  const int *Wb = W + (size_t)(bx * 128 + srow) * KDIM + skof;
  const float *Sb = S + (size_t)(bx * 128 + srow) * NGROUPS;

  f32x4 acc[4][4] = {};
  float4 ar[8];
  int4 wr[8];
  float sc;

#pragma unroll
  for (int u = 0; u < 8; ++u) {
    ar[u] = *(const float4 *)(Ab + u * 4);
    wr[u] = *(const int4 *)(Wb + u * 4);
  }
  sc = Sb[0];

  const int fr = lane & 15;
  const int fq = lane >> 4;
  const int kbase = fq * 8;

  for (int kt = 0; kt < KDIM / 64; ++kt) {
    __syncthreads();
    _Float16 *Ad = &Asf[srow * 64 + skof];
    _Float16 *Bd = &Bsf[srow * 64 + skof];
#pragma unroll
    for (int u = 0; u < 4; ++u) {
      const float4 a0 = ar[2 * u], a1 = ar[2 * u + 1];
      const int4 b0 = wr[2 * u], b1 = wr[2 * u + 1];
      f16x8 ha, hb;
      ha[0] = (_Float16)a0.x; ha[1] = (_Float16)a0.y;
      ha[2] = (_Float16)a0.z; ha[3] = (_Float16)a0.w;
      ha[4] = (_Float16)a1.x; ha[5] = (_Float16)a1.y;
      ha[6] = (_Float16)a1.z; ha[7] = (_Float16)a1.w;
      hb[0] = (_Float16)((float)b0.x * sc); hb[1] = (_Float16)((float)b0.y * sc);
      hb[2] = (_Float16)((float)b0.z * sc); hb[3] = (_Float16)((float)b0.w * sc);
      hb[4] = (_Float16)((float)b1.x * sc); hb[5] = (_Float16)((float)b1.y * sc);
      hb[6] = (_Float16)((float)b1.z * sc); hb[7] = (_Float16)((float)b1.w * sc);
      *(f16x8 *)(Ad + u * 8) = ha;
      *(f16x8 *)(Bd + u * 8) = hb;
    }
    if (kt + 1 < KDIM / 64) {
      const float *An = Ab + (kt + 1) * 64;
      const int *Wn = Wb + (kt + 1) * 64;
#pragma unroll
      for (int u = 0; u < 8; ++u) {
        ar[u] = *(const float4 *)(An + u * 4);
        wr[u] = *(const int4 *)(Wn + u * 4);
      }
      sc = Sb[(kt + 1) >> 1];
    }
    __syncthreads();
#pragma unroll
    for (int ks = 0; ks < 2; ++ks) {
      f16x8 afv[4], bfv[4];
      const int kof = ks * 32 + kbase;
#pragma unroll
      for (int i = 0; i < 4; ++i) {
        afv[i] = *(const f16x8 *)&Asf[(wm * 64 + i * 16 + fr) * 64 + kof];
        bfv[i] = *(const f16x8 *)&Bsf[(wn * 64 + i * 16 + fr) * 64 + kof];
      }
#pragma unroll
      for (int i = 0; i < 4; ++i)
#pragma unroll
        for (int j = 0; j < 4; ++j)
          acc[i][j] = __builtin_amdgcn_mfma_f32_16x16x32_f16(afv[i], bfv[j],
                                                             acc[i][j], 0, 0, 0);
    }
  }

  float *Cb = C + (size_t)(by * 128 + wm * 64) * NDIM + bx * 128 + wn * 64;
#pragma unroll
  for (int i = 0; i < 4; ++i)
#pragma unroll
    for (int j = 0; j < 4; ++j)
#pragma unroll
      for (int r = 0; r < 4; ++r)
        Cb[(size_t)(i * 16 + fq * 4 + r) * NDIM + j * 16 + fr] = acc[i][j][r];
}

extern "C" void kernel_launch(void *const *d_in, const int *in_sizes, int n_in,
                              void *d_out, int out_size, void *d_ws,
                              size_t ws_size, hipStream_t stream) {
  (void)in_sizes; (void)n_in; (void)out_size;
  const float *A = (const float *)d_in[0];
  const int *W = (const int *)d_in[1];
  const float *S = (const float *)d_in[2];
  float *C = (float *)d_out;

  const size_t needA = (size_t)MDIM * KDIM * sizeof(_Float16);
  const size_t needW = (size_t)NDIM * KDIM * sizeof(_Float16);

  if (ws_size >= needA + needW) {
    _Float16 *Ahp = (_Float16 *)d_ws;
    _Float16 *Whp = (_Float16 *)((char *)d_ws + needA);
    cvt_a_kernel<<<2048, 256, 0, stream>>>(A, Ahp);
    cvt_w_kernel<<<2048, 256, 0, stream>>>(W, S, Whp);
    gemm_8phase<<<(MDIM / BM) * (NDIM / BN), 512, 0, stream>>>(Ahp, Whp, C);
  } else {
    dim3 grid(NDIM / 128, MDIM / 128);
    gemm_fused<<<grid, 256, 0, stream>>>(A, W, S, C);
  }
}